// Round 1
// 473.295 us; speedup vs baseline: 1.1085x; 1.1085x over previous
//
#include <hip/hip_runtime.h>
#include <hip/hip_bf16.h>

#define DIM 512
#define BM 64

typedef __bf16 bf16x8 __attribute__((ext_vector_type(8)));
typedef float f32x16 __attribute__((ext_vector_type(16)));

union B128 { uint4 u; bf16x8 v; };

__device__ __forceinline__ unsigned short f2bf(float f) {
    union { __hip_bfloat16 b; unsigned short u; } c;
    c.b = __float2bfloat16(f);
    return c.u;
}

// S_frag: B-fragment-linear layout of S = A + A^T (bf16).
// chunk c = (nt2*32 + ks)*64 + l   (16 B = 8 bf16 each):
//   content = S[e][d0 .. d0+7],  e = nt2*32 + (l&31),  d0 = ks*16 + (l>>5)*8
// => a wave's B-fragment load for (nt2, ks) is 64 consecutive 16B chunks
//    (one fully-coalesced global_load_dwordx4, L2-resident).
__global__ void prep_s_kernel(const float* __restrict__ A,
                              unsigned short* __restrict__ Sf) {
    const int c   = blockIdx.x * 256 + threadIdx.x;   // 0..32767
    const int l   = c & 63;
    const int ks  = (c >> 6) & 31;
    const int nt2 = c >> 11;
    const int e   = nt2 * 32 + (l & 31);
    const int d0  = ks * 16 + (l >> 5) * 8;
    float4 r0 = *(const float4*)(A + (size_t)e * DIM + d0);
    float4 r1 = *(const float4*)(A + (size_t)e * DIM + d0 + 4);
    float cl[8];
    #pragma unroll
    for (int j = 0; j < 8; ++j) cl[j] = A[(size_t)(d0 + j) * DIM + e];
    ushort4 o0, o1;
    o0.x = f2bf(r0.x + cl[0]); o0.y = f2bf(r0.y + cl[1]);
    o0.z = f2bf(r0.z + cl[2]); o0.w = f2bf(r0.w + cl[3]);
    o1.x = f2bf(r1.x + cl[4]); o1.y = f2bf(r1.y + cl[5]);
    o1.z = f2bf(r1.z + cl[6]); o1.w = f2bf(r1.w + cl[7]);
    *(ushort4*)(Sf + (size_t)c * 8)     = o0;
    *(ushort4*)(Sf + (size_t)c * 8 + 4) = o1;
}

// out[b][0:512]   = p[b] + q[b] . S^T   (S symmetric)
// out[b][512:1024]= q[b]                 (exact fp32 copy, fused into staging)
//
// Structure: stage whole q tile once (1 barrier) -> barrier-free K loop with
// B frags straight from L2 -> LDS-transpose vectorized epilogue.
__global__ __launch_bounds__(512, 4) void fused_gemm_kernel(
        const float* __restrict__ pq,
        const unsigned short* __restrict__ Sf,
        float* __restrict__ out) {
    // 64 KB: q tile in A-fragment-linear layout (bf16), reused as f32 for epilogue
    __shared__ __align__(16) unsigned char smem[65536];
    unsigned short* As = (unsigned short*)smem;
    float*          Cs = (float*)smem;

    const int t  = threadIdx.x;
    const int l  = t & 63;
    const int w  = t >> 6;          // wave 0..7
    const int wm = w >> 2;          // 0..1  (M position, 32 rows)
    const int wn = w & 3;           // 0..3  (N position within 128-chunk)
    const int lane31 = l & 31;
    const int half   = l >> 5;
    const int m0 = blockIdx.x * BM;

    // ---- stage q: 64x512 fp32 -> bf16 frag-linear LDS; exact q copy to out.
    // A-chunk (mt, ks, lane lp) holds q[m0+32*mt+(lp&31)][ks*16+(lp>>5)*8 ..+7],
    // stored at chunk index (mt*32+ks)*64 + (lp ^ (ks&7))  [XOR: bank-spread the
    // writes (ks stride is 1024 B == bank-aliasing) while frag reads stay a
    // permutation of one contiguous 1 KB region -> both sides conflict-free].
    #pragma unroll 4
    for (int p = 0; p < 16; ++p) {
        const int u   = p * 512 + t;
        const int row = u >> 7;              // 0..63
        const int col = (u & 127) * 4;       // 0..508
        const size_t goff = (size_t)(m0 + row) * (2 * DIM) + DIM + col;
        float4 qv = *(const float4*)(pq + goff);
        *(float4*)(out + goff) = qv;         // fused exact q copy
        ushort4 qb;
        qb.x = f2bf(qv.x); qb.y = f2bf(qv.y); qb.z = f2bf(qv.z); qb.w = f2bf(qv.w);
        const int mt   = row >> 5;
        const int ks   = col >> 4;
        const int lpos = (row & 31) + ((col >> 3) & 1) * 32;
        const int chunk = (mt * 32 + ks) * 64 + (lpos ^ (ks & 7));
        *(ushort4*)(As + chunk * 8 + (col & 7)) = qb;   // 8 B, aligned
    }
    __syncthreads();

    f32x16 acc[4];
    #pragma unroll
    for (int nt = 0; nt < 4; ++nt)
        #pragma unroll
        for (int r = 0; r < 16; ++r) acc[nt][r] = 0.0f;

    // ---- K loop: NO barriers. 1 conflict-free ds_read_b128 (A frag) +
    // 4 coalesced L2 dwordx4 (B frags) + 4 independent MFMA chains per step.
    #pragma unroll 2
    for (int ks = 0; ks < 32; ++ks) {
        B128 a;
        const int achunk = (wm * 32 + ks) * 64 + (l ^ (ks & 7));
        a.u = *(const uint4*)(As + achunk * 8);
        #pragma unroll
        for (int nt = 0; nt < 4; ++nt) {
            const int nt2 = nt * 4 + wn;
            B128 b;
            b.u = *(const uint4*)(Sf + (size_t)((nt2 * 32 + ks) * 64 + l) * 8);
            acc[nt] = __builtin_amdgcn_mfma_f32_32x32x16_bf16(a.v, b.v, acc[nt], 0, 0, 0);
        }
    }

    // ---- epilogue: transpose acc through LDS (reuse q buffer), then fully
    // vectorized p-load + add + store. Two 256-col halves (64x256 f32 = 64 KB).
    // C/D layout (verified m74/m101): col = lane&31, row = (r&3)+8*(r>>2)+4*(lane>>5)
    #pragma unroll
    for (int h = 0; h < 2; ++h) {
        __syncthreads();   // h=0: K-loop LDS reads done; h=1: prev half reads done
        #pragma unroll
        for (int i = 0; i < 2; ++i) {
            const int nt = 2 * h + i;
            const int colb = 128 * i + 32 * wn + lane31;   // 0..255 within half
            #pragma unroll
            for (int r = 0; r < 16; ++r) {
                const int row = 32 * wm + 4 * half + (r & 3) + 8 * (r >> 2);
                Cs[row * 256 + colb] = acc[nt][r];
            }
        }
        __syncthreads();
        #pragma unroll
        for (int i = 0; i < 8; ++i) {
            const int row = i * 8 + w;          // each wave owns full rows
            const int c0  = l * 4;
            float4 v = *(const float4*)(Cs + row * 256 + c0);
            const size_t goff = (size_t)(m0 + row) * (2 * DIM) + 256 * h + c0;
            float4 pv = *(const float4*)(pq + goff);
            v.x += pv.x; v.y += pv.y; v.z += pv.z; v.w += pv.w;
            *(float4*)(out + goff) = v;
        }
    }
}

extern "C" void kernel_launch(void* const* d_in, const int* in_sizes, int n_in,
                              void* d_out, int out_size, void* d_ws, size_t ws_size,
                              hipStream_t stream) {
    const float* pq = (const float*)d_in[0];
    const float* A  = (const float*)d_in[1];
    float* out = (float*)d_out;
    unsigned short* Sf = (unsigned short*)d_ws;   // 512*512*2 = 512 KB scratch

    prep_s_kernel<<<(DIM * DIM / 8) / 256, 256, 0, stream>>>(A, Sf);
    fused_gemm_kernel<<<65536 / BM, 512, 0, stream>>>(pq, Sf, out);
}